// Round 8
// baseline (426.446 us; speedup 1.0000x reference)
//
#include <hip/hip_runtime.h>

#define NUM_RELS 19

typedef _Float16 half8 __attribute__((ext_vector_type(8)));
typedef float floatx4 __attribute__((ext_vector_type(4)));

// Direct counting sort on key = dst*19 + etype.
// seg[key] counts -> 3-pass exclusive scan -> cursor; scatter writes recs2[pos] = src<<5|etype
// directly in final order (node-major, etype-sorted within node). rowptr[v] = cursor[v*19].
// recs2 record: src(17b)<<5 | etype(5b)  (matches round-6 edge23's proven format)

// ---------------- W2 -> f16 B-fragment swizzle + seg zero ----------------

__global__ __launch_bounds__(512) void w2z_kernel(const float* __restrict__ W2,
                                                  _Float16* __restrict__ W2F,
                                                  int* __restrict__ seg, int M) {
    int idx = blockIdx.x * 512 + threadIdx.x;
    if (idx < NUM_RELS * 2 * 64 * 8) {
        int j = idx & 7, lane = (idx >> 3) & 63, nt = (idx >> 9) & 1, r = idx >> 10;
        int k = (lane >> 4) * 8 + j, n = nt * 16 + (lane & 15);
        W2F[idx] = (_Float16)W2[r * 1024 + k * 32 + n];
    }
    for (int i = idx; i < M; i += gridDim.x * 512) seg[i] = 0;
}

// ---------------- per-(node,etype) histogram: fire-and-forget global atomics ----------------

__global__ __launch_bounds__(256) void hist_kernel(const int* __restrict__ dst,
                                                   const int* __restrict__ etype,
                                                   int* __restrict__ seg, int E) {
    int i0 = blockIdx.x * 256 + threadIdx.x;
    for (int e = i0; e < E; e += gridDim.x * 256)
        atomicAdd(&seg[dst[e] * NUM_RELS + etype[e]], 1);
}

// ---------------- scan pass 1: block-local exclusive scan + block totals ----------------

__global__ __launch_bounds__(512) void scan1_kernel(const int* __restrict__ seg,
                                                    int* __restrict__ cursor,
                                                    int* __restrict__ btot, int M) {
    __shared__ int lds[512];
    int t = threadIdx.x;
    int i = blockIdx.x * 512 + t;
    int v = (i < M) ? seg[i] : 0;
    lds[t] = v;
    __syncthreads();
    for (int off = 1; off < 512; off <<= 1) {
        int x = (t >= off) ? lds[t - off] : 0;
        __syncthreads();
        lds[t] += x;
        __syncthreads();
    }
    if (i < M) cursor[i] = lds[t] - v;           // exclusive, block-local
    if (t == 511) btot[blockIdx.x] = lds[511];
}

// ---------------- scan pass 2: single-block scan of block totals ----------------

__global__ __launch_bounds__(512) void scan2_kernel(const int* __restrict__ btot,
                                                    int* __restrict__ bbase, int NB) {
    __shared__ int lds[512];
    __shared__ int run;
    int t = threadIdx.x;
    if (t == 0) run = 0;
    __syncthreads();
    for (int c = 0; c < NB; c += 512) {
        int i = c + t;
        int v = (i < NB) ? btot[i] : 0;
        lds[t] = v;
        __syncthreads();
        for (int off = 1; off < 512; off <<= 1) {
            int x = (t >= off) ? lds[t - off] : 0;
            __syncthreads();
            lds[t] += x;
            __syncthreads();
        }
        if (i < NB) bbase[i] = run + lds[t] - v;
        __syncthreads();
        if (t == 0) run += lds[511];
        __syncthreads();
    }
}

// ---------------- scan pass 3: add block bases; extract rowptr ----------------

__global__ __launch_bounds__(512) void addback_kernel(int* __restrict__ cursor,
                                                      const int* __restrict__ bbase,
                                                      int* __restrict__ rowptr, int M) {
    int i = blockIdx.x * 512 + threadIdx.x;
    if (i >= M) return;
    int val = cursor[i] + bbase[blockIdx.x];
    cursor[i] = val;
    unsigned q = (unsigned)i / NUM_RELS;
    if ((unsigned)i == q * NUM_RELS) rowptr[q] = val;   // i == N*19 -> rowptr[N] = E
}

// ---------------- layer 1 from seg counts (h = ones -> agg is just counts) ----------------

__global__ __launch_bounds__(512) void l1_kernel(const int* __restrict__ seg,
                                                 const float* __restrict__ W1,
                                                 const float* __restrict__ b1,
                                                 _Float16* __restrict__ h1, int N) {
    __shared__ int cnts[256 * NUM_RELS];   // 19.5KB
    __shared__ float W1s[NUM_RELS * 32];
    __shared__ float b1s[32];
    int t = threadIdx.x;
    int v0 = blockIdx.x * 256;
    int base = v0 * NUM_RELS;
    int lim = min(256 * NUM_RELS, N * NUM_RELS - base);
    for (int i = t; i < lim; i += 512) cnts[i] = seg[base + i];
    for (int i = t; i < NUM_RELS * 32; i += 512) W1s[i] = W1[i];
    if (t < 32) b1s[t] = b1[t];
    __syncthreads();
    int o = t & 31, hw = t >> 5;
    for (int k = hw; k < 256; k += 16) {
        int v = v0 + k;
        if (v < N) {
            float acc = b1s[o];
            const int* cp = &cnts[k * NUM_RELS];
#pragma unroll
            for (int r = 0; r < NUM_RELS; ++r) acc += (float)cp[r] * W1s[r * 32 + o];
            h1[(size_t)v * 32 + o] = (_Float16)fmaxf(acc, 0.f);
        }
    }
}

// ---------------- scatter: directly to final sorted position ----------------

__global__ __launch_bounds__(256) void scat_kernel(const int* __restrict__ src,
                                                   const int* __restrict__ dst,
                                                   const int* __restrict__ etype,
                                                   int* __restrict__ cursor,
                                                   int* __restrict__ recs2, int E) {
    int i0 = blockIdx.x * 256 + threadIdx.x;
    for (int e = i0; e < E; e += gridDim.x * 256) {
        int et = etype[e];
        int key = dst[e] * NUM_RELS + et;
        int pos = atomicAdd(&cursor[key], 1);
        recs2[pos] = (src[e] << 5) | et;
    }
}

// ---------------- Edge aggregation + W2 MFMA + layer 3, fused (round-6 proven, 113us) ----------------
// Per block: 16 nodes, one half-wave each. WRITE-THROUGH run accumulation:
// recs2 is etype-sorted per node, so r is non-decreasing. Run sum kept in a REGISTER;
// every edge, plain ds_write to aggn[r*32+o] (last write of a run wins). Run-boundary
// reset is a v_cndmask. Only loop-carried dep is acc (~6cy VALU); 4-unroll keeps 4 h1
// gathers in flight.

#define AGG_STRIDE (NUM_RELS * 32 + 4)   // 612 floats; +4 keeps MFMA ds_read ~2-way

__global__ __launch_bounds__(512) void edge23_kernel(
    const _Float16* __restrict__ h1, const int* __restrict__ row_start,
    const int* __restrict__ rend, const int* __restrict__ recs2,
    const _Float16* __restrict__ W2F,
    const float* __restrict__ b2, const float* __restrict__ W3, const float* __restrict__ b3,
    float* __restrict__ out, int N) {
    __shared__ float agg[16 * AGG_STRIDE];   // 39.2KB
    __shared__ float h2t[16 * 32];
    __shared__ float W3s[1024];
    __shared__ float b2s[32], b3s[32];
    int t = threadIdx.x;
    for (int i = t; i < 16 * AGG_STRIDE; i += 512) agg[i] = 0.f;
    for (int i = t; i < 1024; i += 512) W3s[i] = W3[i];
    if (t < 32) {
        b2s[t] = b2[t];
        b3s[t] = b3[t];
    }
    __syncthreads();

    int o = t & 31;
    int hw = t >> 5;                    // 16 half-waves = 16 nodes
    int node = blockIdx.x * 16 + hw;
    if (node < N) {
        int start = row_start[node], end = rend[node];
        float* aggn = agg + hw * AGG_STRIDE + o;
        float acc = 0.f;
        int prev_r = -1;
        for (int base = start; base < end; base += 32) {
            int idx = base + o;
            int m_l = (idx < end) ? recs2[idx] : 0;
            int cnt = min(32, end - base);
            int j = 0;
            for (; j + 4 <= cnt; j += 4) {
                int m0 = __shfl(m_l, j, 32);
                int m1 = __shfl(m_l, j + 1, 32);
                int m2 = __shfl(m_l, j + 2, 32);
                int m3 = __shfl(m_l, j + 3, 32);
                float v0 = (float)h1[(size_t)(m0 >> 5) * 32 + o];
                float v1 = (float)h1[(size_t)(m1 >> 5) * 32 + o];
                float v2 = (float)h1[(size_t)(m2 >> 5) * 32 + o];
                float v3 = (float)h1[(size_t)(m3 >> 5) * 32 + o];
                int r0 = m0 & 31, r1 = m1 & 31, r2 = m2 & 31, r3 = m3 & 31;
                acc = (r0 == prev_r) ? (acc + v0) : v0;
                aggn[r0 * 32] = acc;
                acc = (r1 == r0) ? (acc + v1) : v1;
                aggn[r1 * 32] = acc;
                acc = (r2 == r1) ? (acc + v2) : v2;
                aggn[r2 * 32] = acc;
                acc = (r3 == r2) ? (acc + v3) : v3;
                aggn[r3 * 32] = acc;
                prev_r = r3;
            }
            for (; j < cnt; ++j) {
                int m = __shfl(m_l, j, 32);
                int r = m & 31;
                float v = (float)h1[(size_t)(m >> 5) * 32 + o];
                acc = (r == prev_r) ? (acc + v) : v;
                aggn[r * 32] = acc;
                prev_r = r;
            }
        }
    }
    __syncthreads();

    // MFMA: waves 0/1 handle output halves nt=0/1; C accumulates over relations
    int lane = t & 63;
    int wv = t >> 6;
    if (wv < 2) {
        int nt = wv;
        floatx4 accd = {0.f, 0.f, 0.f, 0.f};
        const float* ap0 = agg + (lane & 15) * AGG_STRIDE + (lane >> 4) * 8;
        for (int r = 0; r < NUM_RELS; ++r) {
            const float* ap = ap0 + r * 32;
            half8 a;
#pragma unroll
            for (int j = 0; j < 8; ++j) a[j] = (_Float16)ap[j];
            half8 bfrag = *(const half8*)(W2F + ((r * 2 + nt) * 64 + lane) * 8);
            accd = __builtin_amdgcn_mfma_f32_16x16x32_f16(a, bfrag, accd, 0, 0, 0);
        }
        int col = lane & 15, rowb = (lane >> 4) * 4;
#pragma unroll
        for (int reg = 0; reg < 4; ++reg) {
            h2t[(rowb + reg) * 32 + nt * 16 + col] = fmaxf(accd[reg] + b2s[nt * 16 + col], 0.f);
        }
    }
    __syncthreads();

    if (node < N) {
        float h2v = h2t[hw * 32 + o];
        float acc3 = b3s[o];
#pragma unroll
        for (int i = 0; i < 32; ++i) {
            float hi = __shfl(h2v, i, 32);
            acc3 = fmaf(hi, W3s[i * 32 + o], acc3);
        }
        out[(size_t)node * 32 + o] = acc3;
    }
}

// ---------------- Host launcher ----------------

extern "C" void kernel_launch(void* const* d_in, const int* in_sizes, int n_in,
                              void* d_out, int out_size, void* d_ws, size_t ws_size,
                              hipStream_t stream) {
    const int* src   = (const int*)d_in[0];
    const int* dst   = (const int*)d_in[1];
    const int* etype = (const int*)d_in[2];
    const float* W1  = (const float*)d_in[4];
    const float* b1  = (const float*)d_in[5];
    const float* W2  = (const float*)d_in[6];
    const float* b2  = (const float*)d_in[7];
    const float* W3  = (const float*)d_in[8];
    const float* b3  = (const float*)d_in[9];
    float* out = (float*)d_out;

    int E = in_sizes[0];
    int N = out_size / 32;
    int M = N * NUM_RELS + 1;                 // +1 guard -> rowptr[N] = E
    int NB = (M + 511) / 512;                 // scan blocks (3712 for N=100000)

    char* ws = (char*)d_ws;
    size_t off = 0;
    auto alloc = [&](size_t bytes) {
        void* p = ws + off;
        off = (off + bytes + 255) & ~(size_t)255;
        return p;
    };
    int* seg     = (int*)alloc((size_t)M * 4);
    int* cursor  = (int*)alloc((size_t)M * 4);
    int* btot    = (int*)alloc((size_t)NB * 4);
    int* bbase   = (int*)alloc((size_t)NB * 4);
    int* rowptr  = (int*)alloc(((size_t)N + 2) * 4);
    int* recs2   = (int*)alloc(((size_t)E + 64) * 4);
    _Float16* h1 = (_Float16*)alloc(((size_t)N + 256) * 32 * 2);
    _Float16* W2F = (_Float16*)alloc((size_t)NUM_RELS * 2 * 64 * 8 * 2);

    w2z_kernel<<<512, 512, 0, stream>>>(W2, W2F, seg, M);
    hist_kernel<<<1024, 256, 0, stream>>>(dst, etype, seg, E);
    scan1_kernel<<<NB, 512, 0, stream>>>(seg, cursor, btot, M);
    scan2_kernel<<<1, 512, 0, stream>>>(btot, bbase, NB);
    addback_kernel<<<NB, 512, 0, stream>>>(cursor, bbase, rowptr, M);
    l1_kernel<<<(N + 255) / 256, 512, 0, stream>>>(seg, W1, b1, h1, N);
    scat_kernel<<<1024, 256, 0, stream>>>(src, dst, etype, cursor, recs2, E);

    edge23_kernel<<<(N + 15) / 16, 512, 0, stream>>>(h1, rowptr, rowptr + 1, recs2, W2F,
                                                     b2, W3, b3, out, N);
}

// Round 9
// 253.974 us; speedup vs baseline: 1.6791x; 1.6791x over previous
//
#include <hip/hip_runtime.h>

#define NUM_RELS 19
#define NPB 256        // nodes per bucket
#define NPB_SHIFT 8
#define MAXB 400       // max buckets (N <= 102400)
#define NBLKS 256      // locsort blocks (1/CU)
#define CHUNK_MAX 8192 // max edges per locsort block (E <= 2.09M)
#define BSTAGE 8192    // max edges per bucket (Poisson(4096), 64-sigma headroom)

typedef _Float16 half8 __attribute__((ext_vector_type(8)));
typedef float floatx4 __attribute__((ext_vector_type(4)));

// rec (recs4): dstlocal(8b)<<22 | src(17b)<<5 | etype(5b)
// recs2 = rec & 0x3FFFFF -> src<<5 | etype  (node-major, etype-sorted within node)

// ---------------- W2 -> f16 B-fragment swizzle + bcnt zero ----------------

__global__ void w2z_kernel(const float* __restrict__ W2, _Float16* __restrict__ W2F,
                           int* __restrict__ bcnt) {
    int idx = blockIdx.x * 256 + threadIdx.x;
    if (idx < MAXB) bcnt[idx] = 0;
    if (idx >= NUM_RELS * 2 * 64 * 8) return;
    int j = idx & 7, lane = (idx >> 3) & 63, nt = (idx >> 9) & 1, r = idx >> 10;
    int k = (lane >> 4) * 8 + j, n = nt * 16 + (lane & 15);
    W2F[idx] = (_Float16)W2[r * 1024 + k * 32 + n];
}

// ---------------- fused block-local counting sort (ONE edge-data pass) ----------------
// Per block: hist chunk by bucket (LDS atomic), scan, scatter records into LDS stage,
// stream stage to recs4 region COALESCED. No global scatter anywhere.

__global__ __launch_bounds__(512) void locsort_kernel(
    const int* __restrict__ src, const int* __restrict__ dst, const int* __restrict__ etype,
    unsigned* __restrict__ recs4, int* __restrict__ blkhist, int* __restrict__ locoffs,
    int* __restrict__ bcnt, int E, int B, int chunk) {
    __shared__ int hist[MAXB];
    __shared__ int cur[MAXB];
    __shared__ int lds[512];
    __shared__ unsigned stage[CHUNK_MAX];   // 32KB
    int t = threadIdx.x, blk = blockIdx.x;
    for (int i = t; i < B; i += 512) hist[i] = 0;
    __syncthreads();
    int e0 = blk * chunk, e1 = min(E, e0 + chunk);
    for (int e = e0 + t; e < e1; e += 512)
        atomicAdd(&hist[dst[e] >> NPB_SHIFT], 1);
    __syncthreads();
    int c = (t < B) ? hist[t] : 0;
    lds[t] = c;
    __syncthreads();
    for (int off = 1; off < 512; off <<= 1) {
        int x = (t >= off) ? lds[t - off] : 0;
        __syncthreads();
        lds[t] += x;
        __syncthreads();
    }
    int excl = lds[t] - c;
    if (t < B) {
        cur[t] = excl;
        blkhist[blk * MAXB + t] = c;      // coalesced
        locoffs[blk * MAXB + t] = excl;   // coalesced
        if (c) atomicAdd(&bcnt[t], c);
    }
    __syncthreads();
    for (int e = e0 + t; e < e1; e += 512) {
        int d = dst[e];
        int pos = atomicAdd(&cur[d >> NPB_SHIFT], 1);
        stage[pos] = ((unsigned)(d & (NPB - 1)) << 22) | ((unsigned)src[e] << 5) | (unsigned)etype[e];
    }
    __syncthreads();
    int n = e1 - e0;
    for (int i = t; i < n; i += 512) recs4[(size_t)blk * chunk + i] = stage[i];  // coalesced
}

// ---------------- bucket bases: 1-block exclusive scan of padded bcnt ----------------

__global__ __launch_bounds__(512) void pscan_kernel(const int* __restrict__ bcnt,
                                                    int* __restrict__ pbase, int B) {
    __shared__ int lds[512];
    int t = threadIdx.x;
    int c = (t < B) ? ((bcnt[t] + 7) & ~7) : 0;
    lds[t] = c;
    __syncthreads();
    for (int off = 1; off < 512; off <<= 1) {
        int x = (t >= off) ? lds[t - off] : 0;
        __syncthreads();
        lds[t] += x;
        __syncthreads();
    }
    if (t < B) pbase[t] = lds[t] - c;
}

// ---------------- bucket sort (etype-sub-sorted) + layer1, single recs4 read ----------------
// Gather the bucket's 256 slices into LDS stage (slice index arrays are L3-resident),
// then r6-proven in-LDS counting sort by (node,etype) + l1 + rescatter to recs2.

__global__ __launch_bounds__(512) void bsort_l1_kernel(
    const unsigned* __restrict__ recs4, const int* __restrict__ blkhist,
    const int* __restrict__ locoffs, const int* __restrict__ pbase,
    int* __restrict__ recs2, int* __restrict__ row_start, int* __restrict__ rend,
    const float* __restrict__ W1, const float* __restrict__ b1,
    _Float16* __restrict__ h1, int N, int chunk) {
    __shared__ unsigned stage[BSTAGE];       // 32KB
    __shared__ int cnt2[NPB * NUM_RELS];     // 19.4KB
    __shared__ int offsl[NPB];
    __shared__ int lds[512];
    __shared__ float W1s[NUM_RELS * 32];
    __shared__ float b1s[32];
    __shared__ int ntot;
    int bkt = blockIdx.x;
    int t = threadIdx.x;
    int p0 = pbase[bkt];

    for (int k = t; k < NPB * NUM_RELS; k += 512) cnt2[k] = 0;
    for (int k = t; k < NUM_RELS * 32; k += 512) W1s[k] = W1[k];
    if (t < 32) b1s[t] = b1[t];

    int len = 0, sstart = 0;
    if (t < NBLKS) {
        len = blkhist[t * MAXB + bkt];
        sstart = t * chunk + locoffs[t * MAXB + bkt];
    }
    lds[t] = len;
    __syncthreads();
    for (int off = 1; off < 512; off <<= 1) {
        int x = (t >= off) ? lds[t - off] : 0;
        __syncthreads();
        lds[t] += x;
        __syncthreads();
    }
    int sbase = lds[t] - len;
    if (t == 511) ntot = lds[511];
    __syncthreads();
    for (int k = 0; k < len; ++k) stage[sbase + k] = recs4[sstart + k];
    __syncthreads();
    int n = ntot;

    for (int k = t; k < n; k += 512) {
        unsigned rec = stage[k];
        atomicAdd(&cnt2[(rec >> 22) * NUM_RELS + (rec & 31)], 1);
    }
    __syncthreads();
    int c = 0;
    if (t < NPB) {
        const int* cp = &cnt2[t * NUM_RELS];
#pragma unroll
        for (int r = 0; r < NUM_RELS; ++r) c += cp[r];
        offsl[t] = c;
    }
    __syncthreads();
    for (int off = 1; off < NPB; off <<= 1) {
        int x = 0;
        if (t < NPB && t >= off) x = offsl[t - off];
        __syncthreads();
        if (t < NPB) offsl[t] += x;
        __syncthreads();
    }
    int v0n = bkt << NPB_SHIFT;
    if (t < NPB) {
        int start = p0 + offsl[t] - c;
        int v = v0n + t;
        if (v < N) {
            row_start[v] = start;
            rend[v] = start + c;
        }
    }
    __syncthreads();

    // layer 1 from per-(node,etype) counts (h = ones -> agg is just counts)
    int o = t & 31, hw = t >> 5;
    for (int k = hw; k < NPB; k += 16) {
        int vv = v0n + k;
        if (vv < N) {
            float acc = b1s[o];
            const int* cp = &cnt2[k * NUM_RELS];
#pragma unroll
            for (int r = 0; r < NUM_RELS; ++r) acc += (float)cp[r] * W1s[r * 32 + o];
            h1[(size_t)vv * 32 + o] = (_Float16)fmaxf(acc, 0.f);
        }
    }
    __syncthreads();

    if (t < NPB) {
        int base = p0 + offsl[t] - c;
        for (int r = 0; r < NUM_RELS; ++r) {
            int cv = cnt2[t * NUM_RELS + r];
            cnt2[t * NUM_RELS + r] = base;
            base += cv;
        }
    }
    __syncthreads();

    for (int k = t; k < n; k += 512) {
        unsigned rec = stage[k];
        int p = atomicAdd(&cnt2[(rec >> 22) * NUM_RELS + (rec & 31)], 1);
        recs2[p] = (int)(rec & 0x3FFFFFu);
    }
}

// ---------------- Edge aggregation + W2 MFMA + layer 3, fused ----------------
// r6-proven write-through run accumulation, with two micro-opts:
// (a) per-edge record via BROADCAST global load (same addr across half-wave -> one L1
//     transaction) instead of ds_bpermute -> only 1 LDS op/edge (the fire-and-forget write);
// (b) h1 gather via 32-bit byte offset (src<<6 | o<<1) + uniform base -> 1 VALU addr op.
// 8-unroll keeps 8 independent h1 gathers in flight.

#define AGG_STRIDE (NUM_RELS * 32 + 4)

__global__ __launch_bounds__(512) void edge23_kernel(
    const _Float16* __restrict__ h1, const int* __restrict__ row_start,
    const int* __restrict__ rend, const int* __restrict__ recs2,
    const _Float16* __restrict__ W2F,
    const float* __restrict__ b2, const float* __restrict__ W3, const float* __restrict__ b3,
    float* __restrict__ out, int N) {
    __shared__ float agg[16 * AGG_STRIDE];   // 39.2KB
    __shared__ float h2t[16 * 32];
    __shared__ float W3s[1024];
    __shared__ float b2s[32], b3s[32];
    int t = threadIdx.x;
    for (int i = t; i < 16 * AGG_STRIDE; i += 512) agg[i] = 0.f;
    for (int i = t; i < 1024; i += 512) W3s[i] = W3[i];
    if (t < 32) {
        b2s[t] = b2[t];
        b3s[t] = b3[t];
    }
    __syncthreads();

    int o = t & 31;
    int hw = t >> 5;                    // 16 half-waves = 16 nodes
    int node = blockIdx.x * 16 + hw;
    if (node < N) {
        int start = row_start[node], end = rend[node];
        float* aggn = agg + hw * AGG_STRIDE + o;
        const char* h1c = (const char*)h1;
        unsigned ob = (unsigned)(o << 1);
        float acc = 0.f;
        int prev_r = -1;
        int j = start;
        for (; j + 8 <= end; j += 8) {
            int m0 = recs2[j], m1 = recs2[j + 1], m2 = recs2[j + 2], m3 = recs2[j + 3];
            int m4 = recs2[j + 4], m5 = recs2[j + 5], m6 = recs2[j + 6], m7 = recs2[j + 7];
            float v0 = (float)*(const _Float16*)(h1c + (((unsigned)(m0 >> 5) << 6) | ob));
            float v1 = (float)*(const _Float16*)(h1c + (((unsigned)(m1 >> 5) << 6) | ob));
            float v2 = (float)*(const _Float16*)(h1c + (((unsigned)(m2 >> 5) << 6) | ob));
            float v3 = (float)*(const _Float16*)(h1c + (((unsigned)(m3 >> 5) << 6) | ob));
            float v4 = (float)*(const _Float16*)(h1c + (((unsigned)(m4 >> 5) << 6) | ob));
            float v5 = (float)*(const _Float16*)(h1c + (((unsigned)(m5 >> 5) << 6) | ob));
            float v6 = (float)*(const _Float16*)(h1c + (((unsigned)(m6 >> 5) << 6) | ob));
            float v7 = (float)*(const _Float16*)(h1c + (((unsigned)(m7 >> 5) << 6) | ob));
            int r0 = m0 & 31, r1 = m1 & 31, r2 = m2 & 31, r3 = m3 & 31;
            int r4 = m4 & 31, r5 = m5 & 31, r6 = m6 & 31, r7 = m7 & 31;
            acc = (r0 == prev_r) ? (acc + v0) : v0;  aggn[r0 * 32] = acc;
            acc = (r1 == r0) ? (acc + v1) : v1;      aggn[r1 * 32] = acc;
            acc = (r2 == r1) ? (acc + v2) : v2;      aggn[r2 * 32] = acc;
            acc = (r3 == r2) ? (acc + v3) : v3;      aggn[r3 * 32] = acc;
            acc = (r4 == r3) ? (acc + v4) : v4;      aggn[r4 * 32] = acc;
            acc = (r5 == r4) ? (acc + v5) : v5;      aggn[r5 * 32] = acc;
            acc = (r6 == r5) ? (acc + v6) : v6;      aggn[r6 * 32] = acc;
            acc = (r7 == r6) ? (acc + v7) : v7;      aggn[r7 * 32] = acc;
            prev_r = r7;
        }
        for (; j < end; ++j) {
            int m = recs2[j];
            int r = m & 31;
            float v = (float)*(const _Float16*)(h1c + (((unsigned)(m >> 5) << 6) | ob));
            acc = (r == prev_r) ? (acc + v) : v;
            aggn[r * 32] = acc;
            prev_r = r;
        }
    }
    __syncthreads();

    // MFMA: waves 0/1 handle output halves nt=0/1; C accumulates over relations
    int lane = t & 63;
    int wv = t >> 6;
    if (wv < 2) {
        int nt = wv;
        floatx4 accd = {0.f, 0.f, 0.f, 0.f};
        const float* ap0 = agg + (lane & 15) * AGG_STRIDE + (lane >> 4) * 8;
        for (int r = 0; r < NUM_RELS; ++r) {
            const float* ap = ap0 + r * 32;
            half8 a;
#pragma unroll
            for (int j = 0; j < 8; ++j) a[j] = (_Float16)ap[j];
            half8 bfrag = *(const half8*)(W2F + ((r * 2 + nt) * 64 + lane) * 8);
            accd = __builtin_amdgcn_mfma_f32_16x16x32_f16(a, bfrag, accd, 0, 0, 0);
        }
        int col = lane & 15, rowb = (lane >> 4) * 4;
#pragma unroll
        for (int reg = 0; reg < 4; ++reg) {
            h2t[(rowb + reg) * 32 + nt * 16 + col] = fmaxf(accd[reg] + b2s[nt * 16 + col], 0.f);
        }
    }
    __syncthreads();

    if (node < N) {
        float h2v = h2t[hw * 32 + o];
        float acc3 = b3s[o];
#pragma unroll
        for (int i = 0; i < 32; ++i) {
            float hi = __shfl(h2v, i, 32);
            acc3 = fmaf(hi, W3s[i * 32 + o], acc3);
        }
        out[(size_t)node * 32 + o] = acc3;
    }
}

// ---------------- Host launcher ----------------

extern "C" void kernel_launch(void* const* d_in, const int* in_sizes, int n_in,
                              void* d_out, int out_size, void* d_ws, size_t ws_size,
                              hipStream_t stream) {
    const int* src   = (const int*)d_in[0];
    const int* dst   = (const int*)d_in[1];
    const int* etype = (const int*)d_in[2];
    const float* W1  = (const float*)d_in[4];
    const float* b1  = (const float*)d_in[5];
    const float* W2  = (const float*)d_in[6];
    const float* b2  = (const float*)d_in[7];
    const float* W3  = (const float*)d_in[8];
    const float* b3  = (const float*)d_in[9];
    float* out = (float*)d_out;

    int E = in_sizes[0];
    int N = out_size / 32;
    int B = (N + NPB - 1) >> NPB_SHIFT;   // 391 for N=100000
    int chunk = (E + NBLKS - 1) / NBLKS;  // 6250 for E=1.6M (<= CHUNK_MAX)

    char* ws = (char*)d_ws;
    size_t off = 0;
    auto alloc = [&](size_t bytes) {
        void* p = ws + off;
        off = (off + bytes + 255) & ~(size_t)255;
        return p;
    };
    int* bcnt       = (int*)alloc((size_t)MAXB * 4);
    int* pbase      = (int*)alloc((size_t)MAXB * 4);
    int* blkhist    = (int*)alloc((size_t)NBLKS * MAXB * 4);
    int* locoffs    = (int*)alloc((size_t)NBLKS * MAXB * 4);
    int* row_start  = (int*)alloc((size_t)N * 4);
    int* rend       = (int*)alloc((size_t)N * 4);
    unsigned* recs4 = (unsigned*)alloc(((size_t)E + CHUNK_MAX) * 4);
    int* recs2      = (int*)alloc(((size_t)E + 8 * MAXB + 64) * 4);
    _Float16* h1    = (_Float16*)alloc(((size_t)N + NPB) * 32 * 2);
    _Float16* W2F   = (_Float16*)alloc((size_t)NUM_RELS * 2 * 64 * 8 * 2);

    w2z_kernel<<<(NUM_RELS * 2 * 64 * 8 + 255) / 256, 256, 0, stream>>>(W2, W2F, bcnt);
    locsort_kernel<<<NBLKS, 512, 0, stream>>>(src, dst, etype, recs4, blkhist, locoffs,
                                              bcnt, E, B, chunk);
    pscan_kernel<<<1, 512, 0, stream>>>(bcnt, pbase, B);
    bsort_l1_kernel<<<B, 512, 0, stream>>>(recs4, blkhist, locoffs, pbase, recs2,
                                           row_start, rend, W1, b1, h1, N, chunk);
    edge23_kernel<<<(N + 15) / 16, 512, 0, stream>>>(h1, row_start, rend, recs2, W2F,
                                                     b2, W3, b3, out, N);
}